// Round 1
// baseline (71.187 us; speedup 1.0000x reference)
//
#include <hip/hip_runtime.h>

typedef short short8 __attribute__((ext_vector_type(8)));
typedef short short4v __attribute__((ext_vector_type(4)));
typedef float f32x4 __attribute__((ext_vector_type(4)));

#define BM 128
#define BN 128
#define DK 64

// f32 -> bf16 round-to-nearest-even (bit-level, no API dependence)
__device__ __forceinline__ short f2bf(float x) {
    unsigned u = __builtin_bit_cast(unsigned, x);
    unsigned r = (u + 0x7fffu + ((u >> 16) & 1u)) >> 16;
    return (short)r;
}

__global__ __launch_bounds__(256, 2)
void fm_kernel(const float* __restrict__ U, const float* __restrict__ M,
               float* __restrict__ out, int NU, int NM) {
    // bf16 tiles: users, users^2, movies, movies^2. 4 x 16 KB = 64 KB LDS.
    __shared__ short sA[BM * DK];
    __shared__ short sA2[BM * DK];
    __shared__ short sB[BM * DK];
    __shared__ short sB2[BM * DK];

    const int t = threadIdx.x;
    const int lane = t & 63;
    const int w = t >> 6;          // wave id 0..3
    const int wr = w >> 1;         // wave row (2 x 64)
    const int wc = w & 1;          // wave col (2 x 64)
    const int lr = lane & 15;
    const int lk = lane >> 4;

    const int mbase = blockIdx.x * BM;
    const int nbase = blockIdx.y * BN;

    // ---- stage: each thread loads 8 rows x one float4 per matrix ----
    const int r0 = t >> 4;         // 0..15
    const int c4 = t & 15;         // float4 index in row; elem col = c4*4
    const int chunk = c4 >> 1;     // 16B chunk index 0..7
    const int sub = c4 & 1;        // which 8B half of the chunk

#pragma unroll
    for (int i = 0; i < 8; ++i) {
        const int r = r0 + i * 16;                       // 0..127
        // swizzled LDS short-index for this thread's 4 bf16
        const int sidx = r * DK + ((chunk ^ (r & 7)) << 3) + (sub << 2);
        // users
        {
            float4 v = make_float4(0.f, 0.f, 0.f, 0.f);
            const int gr = mbase + r;
            if (gr < NU) v = *(const float4*)(U + (size_t)gr * DK + c4 * 4);
            short4v b  = { f2bf(v.x),     f2bf(v.y),     f2bf(v.z),     f2bf(v.w)     };
            short4v b2 = { f2bf(v.x*v.x), f2bf(v.y*v.y), f2bf(v.z*v.z), f2bf(v.w*v.w) };
            *(short4v*)&sA[sidx]  = b;
            *(short4v*)&sA2[sidx] = b2;
        }
        // movies
        {
            float4 v = make_float4(0.f, 0.f, 0.f, 0.f);
            const int gr = nbase + r;
            if (gr < NM) v = *(const float4*)(M + (size_t)gr * DK + c4 * 4);
            short4v b  = { f2bf(v.x),     f2bf(v.y),     f2bf(v.z),     f2bf(v.w)     };
            short4v b2 = { f2bf(v.x*v.x), f2bf(v.y*v.y), f2bf(v.z*v.z), f2bf(v.w*v.w) };
            *(short4v*)&sB[sidx]  = b;
            *(short4v*)&sB2[sidx] = b2;
        }
    }
    __syncthreads();

    f32x4 accS[4][4];
    f32x4 accQ[4][4];
#pragma unroll
    for (int m = 0; m < 4; ++m)
#pragma unroll
        for (int n = 0; n < 4; ++n) {
            accS[m][n] = (f32x4){0.f, 0.f, 0.f, 0.f};
            accQ[m][n] = (f32x4){0.f, 0.f, 0.f, 0.f};
        }

    // ---- K loop: 2 steps of 32 ----
#pragma unroll
    for (int ks = 0; ks < 2; ++ks) {
        short8 af[4], a2f[4], bfr[4], b2f[4];
        const int c = ks * 4 + lk;   // 16B chunk along K, 0..7
#pragma unroll
        for (int m = 0; m < 4; ++m) {
            const int row = wr * 64 + m * 16 + lr;
            const int idx = row * DK + ((c ^ (row & 7)) << 3);
            af[m]  = *(const short8*)&sA[idx];
            a2f[m] = *(const short8*)&sA2[idx];
        }
#pragma unroll
        for (int n = 0; n < 4; ++n) {
            const int row = wc * 64 + n * 16 + lr;
            const int idx = row * DK + ((c ^ (row & 7)) << 3);
            bfr[n] = *(const short8*)&sB[idx];
            b2f[n] = *(const short8*)&sB2[idx];
        }
#pragma unroll
        for (int m = 0; m < 4; ++m)
#pragma unroll
            for (int n = 0; n < 4; ++n) {
                accS[m][n] = __builtin_amdgcn_mfma_f32_16x16x32_bf16(af[m],  bfr[n], accS[m][n], 0, 0, 0);
                accQ[m][n] = __builtin_amdgcn_mfma_f32_16x16x32_bf16(a2f[m], b2f[n], accQ[m][n], 0, 0, 0);
            }
    }

    // ---- epilogue: out = 0.5*(s^2 - q) ----
    // C/D layout (16x16x32): col = lane&15, row = (lane>>4)*4 + reg
#pragma unroll
    for (int m = 0; m < 4; ++m) {
        const int grow0 = mbase + wr * 64 + m * 16 + lk * 4;
#pragma unroll
        for (int n = 0; n < 4; ++n) {
            const int gcol = nbase + wc * 64 + n * 16 + lr;
            if (gcol < NM) {
                f32x4 s = accS[m][n];
                f32x4 q = accQ[m][n];
#pragma unroll
                for (int r = 0; r < 4; ++r) {
                    const int grow = grow0 + r;
                    if (grow < NU)
                        out[(size_t)grow * NM + gcol] = 0.5f * (s[r] * s[r] - q[r]);
                }
            }
        }
    }
}

extern "C" void kernel_launch(void* const* d_in, const int* in_sizes, int n_in,
                              void* d_out, int out_size, void* d_ws, size_t ws_size,
                              hipStream_t stream) {
    const float* U = (const float*)d_in[0];
    const float* M = (const float*)d_in[1];
    float* out = (float*)d_out;
    const int NU = in_sizes[0] / DK;   // 1024
    const int NM = in_sizes[1] / DK;   // 50000
    dim3 grid((NU + BM - 1) / BM, (NM + BN - 1) / BN);
    fm_kernel<<<grid, dim3(256), 0, stream>>>(U, M, out, NU, NM);
}

// Round 2
// 59.958 us; speedup vs baseline: 1.1873x; 1.1873x over previous
//
#include <hip/hip_runtime.h>

typedef short short8 __attribute__((ext_vector_type(8)));
typedef float f32x4 __attribute__((ext_vector_type(4)));

#define DK 64

// f32 -> bf16 round-to-nearest-even
__device__ __forceinline__ short f2bf(float x) {
    unsigned u = __builtin_bit_cast(unsigned, x);
    unsigned r = (u + 0x7fffu + ((u >> 16) & 1u)) >> 16;
    return (short)r;
}

__device__ __forceinline__ void gl_lds16(const void* g, void* l) {
    __builtin_amdgcn_global_load_lds(
        (const __attribute__((address_space(1))) unsigned int*)g,
        (__attribute__((address_space(3))) unsigned int*)l, 16, 0, 0);
}

// ---------------- Phase 1: convert to bf16 (value + square), pre-swizzled ----
// ws layout (shorts): [wsU: NUP*64][wsU2: NUP*64][wsM: NMP*64][wsM2: NMP*64]
// Swizzle: ws[row][p (16B chunk)] = orig[row][p ^ (row&7)] so that a LINEAR
// global_load_lds copy yields the XOR-swizzled LDS layout the GEMM reads.
__global__ __launch_bounds__(256)
void fm_convert(const float* __restrict__ U, const float* __restrict__ M,
                short* __restrict__ ws, int NU, int NM, int NUP, int NMP) {
    int id = blockIdx.x * blockDim.x + threadIdx.x;
    int total = (NUP + NMP) * 8;
    if (id >= total) return;
    int rowg = id >> 3;
    int p = id & 7;
    const float* src; short *dv, *dq; int row, nvalid;
    if (rowg < NUP) {
        row = rowg; src = U; dv = ws; dq = ws + (size_t)NUP * DK; nvalid = NU;
    } else {
        row = rowg - NUP; src = M;
        dv = ws + (size_t)2 * NUP * DK; dq = dv + (size_t)NMP * DK; nvalid = NM;
    }
    short8 v8 = {0,0,0,0,0,0,0,0}, q8 = {0,0,0,0,0,0,0,0};
    if (row < nvalid) {
        int cp = p ^ (row & 7);
        const float* s = src + (size_t)row * DK + cp * 8;
        float4 a = *(const float4*)(s);
        float4 b = *(const float4*)(s + 4);
        v8 = (short8){ f2bf(a.x), f2bf(a.y), f2bf(a.z), f2bf(a.w),
                       f2bf(b.x), f2bf(b.y), f2bf(b.z), f2bf(b.w) };
        q8 = (short8){ f2bf(a.x*a.x), f2bf(a.y*a.y), f2bf(a.z*a.z), f2bf(a.w*a.w),
                       f2bf(b.x*b.x), f2bf(b.y*b.y), f2bf(b.z*b.z), f2bf(b.w*b.w) };
    }
    *(short8*)(dv + (size_t)row * DK + p * 8) = v8;
    *(short8*)(dq + (size_t)row * DK + p * 8) = q8;
}

// ---------------- Phase 2: fused double-GEMM, 64x128 tile, 4 waves ----------
#define BM 64
#define BN 128

__global__ __launch_bounds__(256, 3)
void fm_gemm(const short* __restrict__ ws, float* __restrict__ out,
             int NM, int NMP, int NUP) {
    __shared__ short sA [BM * DK];   // 8 KB
    __shared__ short sA2[BM * DK];   // 8 KB
    __shared__ short sB [BN * DK];   // 16 KB
    __shared__ short sB2[BN * DK];   // 16 KB  -> 48 KB total

    const int t = threadIdx.x;
    const int lane = t & 63;
    const int w = t >> 6;          // wave 0..3
    const int wr = w >> 1;         // 2 wave-rows x 32
    const int wc = w & 1;          // 2 wave-cols x 64
    const int lr = lane & 15;
    const int lk = lane >> 4;

    const int mbase = blockIdx.x * BM;
    const int nbase = blockIdx.y * BN;

    const short* gU  = ws;
    const short* gU2 = ws + (size_t)NUP * DK;
    const short* gM  = ws + (size_t)2 * NUP * DK;
    const short* gM2 = gM + (size_t)NMP * DK;

    // Staging: pure linear copies (ws is pre-swizzled). 1 KB per wave-instr.
    {
        const short* srcA  = gU  + (size_t)mbase * DK;
        const short* srcA2 = gU2 + (size_t)mbase * DK;
        const short* srcB  = gM  + (size_t)nbase * DK;
        const short* srcB2 = gM2 + (size_t)nbase * DK;
        const int lo = lane * 8;                  // shorts: lane*16B
#pragma unroll
        for (int i = 0; i < 2; ++i) {             // A tiles: 8 KB = 8 chunks
            const int ch = w * 2 + i;             // 1KB chunk id
            gl_lds16(srcA  + ch * 512 + lo, sA  + ch * 512);
            gl_lds16(srcA2 + ch * 512 + lo, sA2 + ch * 512);
        }
#pragma unroll
        for (int i = 0; i < 4; ++i) {             // B tiles: 16 KB = 16 chunks
            const int ch = w * 4 + i;
            gl_lds16(srcB  + ch * 512 + lo, sB  + ch * 512);
            gl_lds16(srcB2 + ch * 512 + lo, sB2 + ch * 512);
        }
    }
    __syncthreads();

    f32x4 accS[2][4], accQ[2][4];
#pragma unroll
    for (int m = 0; m < 2; ++m)
#pragma unroll
        for (int n = 0; n < 4; ++n) {
            accS[m][n] = (f32x4){0.f, 0.f, 0.f, 0.f};
            accQ[m][n] = (f32x4){0.f, 0.f, 0.f, 0.f};
        }

#pragma unroll
    for (int ks = 0; ks < 2; ++ks) {
        const int c = ks * 4 + lk;                // 16B K-chunk 0..7
        short8 af[2], a2f[2], bf[4], b2f[4];
#pragma unroll
        for (int m = 0; m < 2; ++m) {
            const int row = wr * 32 + m * 16 + lr;
            const int idx = row * DK + ((c ^ (row & 7)) << 3);
            af[m]  = *(const short8*)&sA [idx];
            a2f[m] = *(const short8*)&sA2[idx];
        }
#pragma unroll
        for (int n = 0; n < 4; ++n) {
            const int row = wc * 64 + n * 16 + lr;
            const int idx = row * DK + ((c ^ (row & 7)) << 3);
            bf[n]  = *(const short8*)&sB [idx];
            b2f[n] = *(const short8*)&sB2[idx];
        }
#pragma unroll
        for (int m = 0; m < 2; ++m)
#pragma unroll
            for (int n = 0; n < 4; ++n) {
                accS[m][n] = __builtin_amdgcn_mfma_f32_16x16x32_bf16(af[m],  bf[n],  accS[m][n], 0, 0, 0);
                accQ[m][n] = __builtin_amdgcn_mfma_f32_16x16x32_bf16(a2f[m], b2f[n], accQ[m][n], 0, 0, 0);
            }
    }

    // Epilogue: out = 0.5*(s^2 - q). C/D: col = lane&15, row = lk*4 + reg
#pragma unroll
    for (int m = 0; m < 2; ++m) {
        const int grow0 = mbase + wr * 32 + m * 16 + lk * 4;
#pragma unroll
        for (int n = 0; n < 4; ++n) {
            const int gcol = nbase + wc * 64 + n * 16 + lr;
            if (gcol < NM) {
                f32x4 s = accS[m][n];
                f32x4 q = accQ[m][n];
#pragma unroll
                for (int r = 0; r < 4; ++r)
                    out[(size_t)(grow0 + r) * NM + gcol] = 0.5f * (s[r] * s[r] - q[r]);
            }
        }
    }
}

// ---------------- Fallback (round-1 kernel, used only if ws too small) ------
__global__ __launch_bounds__(256, 2)
void fm_fallback(const float* __restrict__ U, const float* __restrict__ M,
                 float* __restrict__ out, int NU, int NM) {
    __shared__ short sA [128 * DK];
    __shared__ short sA2[128 * DK];
    __shared__ short sB [128 * DK];
    __shared__ short sB2[128 * DK];

    const int t = threadIdx.x;
    const int lane = t & 63;
    const int w = t >> 6;
    const int wr = w >> 1;
    const int wc = w & 1;
    const int lr = lane & 15;
    const int lk = lane >> 4;

    const int mbase = blockIdx.x * 128;
    const int nbase = blockIdx.y * 128;

    const int r0 = t >> 4;
    const int c4 = t & 15;
    const int chunk = c4 >> 1;
    const int sub = c4 & 1;

    typedef short short4v __attribute__((ext_vector_type(4)));
#pragma unroll
    for (int i = 0; i < 8; ++i) {
        const int r = r0 + i * 16;
        const int sidx = r * DK + ((chunk ^ (r & 7)) << 3) + (sub << 2);
        {
            float4 v = make_float4(0.f, 0.f, 0.f, 0.f);
            const int gr = mbase + r;
            if (gr < NU) v = *(const float4*)(U + (size_t)gr * DK + c4 * 4);
            short4v b  = { f2bf(v.x), f2bf(v.y), f2bf(v.z), f2bf(v.w) };
            short4v b2 = { f2bf(v.x*v.x), f2bf(v.y*v.y), f2bf(v.z*v.z), f2bf(v.w*v.w) };
            *(short4v*)&sA[sidx] = b; *(short4v*)&sA2[sidx] = b2;
        }
        {
            float4 v = make_float4(0.f, 0.f, 0.f, 0.f);
            const int gr = nbase + r;
            if (gr < NM) v = *(const float4*)(M + (size_t)gr * DK + c4 * 4);
            short4v b  = { f2bf(v.x), f2bf(v.y), f2bf(v.z), f2bf(v.w) };
            short4v b2 = { f2bf(v.x*v.x), f2bf(v.y*v.y), f2bf(v.z*v.z), f2bf(v.w*v.w) };
            *(short4v*)&sB[sidx] = b; *(short4v*)&sB2[sidx] = b2;
        }
    }
    __syncthreads();

    f32x4 accS[4][4], accQ[4][4];
#pragma unroll
    for (int m = 0; m < 4; ++m)
#pragma unroll
        for (int n = 0; n < 4; ++n) {
            accS[m][n] = (f32x4){0.f,0.f,0.f,0.f};
            accQ[m][n] = (f32x4){0.f,0.f,0.f,0.f};
        }
#pragma unroll
    for (int ks = 0; ks < 2; ++ks) {
        short8 af[4], a2f[4], bfr[4], b2f[4];
        const int c = ks * 4 + lk;
#pragma unroll
        for (int m = 0; m < 4; ++m) {
            const int row = wr * 64 + m * 16 + lr;
            const int idx = row * DK + ((c ^ (row & 7)) << 3);
            af[m] = *(const short8*)&sA[idx]; a2f[m] = *(const short8*)&sA2[idx];
        }
#pragma unroll
        for (int n = 0; n < 4; ++n) {
            const int row = wc * 64 + n * 16 + lr;
            const int idx = row * DK + ((c ^ (row & 7)) << 3);
            bfr[n] = *(const short8*)&sB[idx]; b2f[n] = *(const short8*)&sB2[idx];
        }
#pragma unroll
        for (int m = 0; m < 4; ++m)
#pragma unroll
            for (int n = 0; n < 4; ++n) {
                accS[m][n] = __builtin_amdgcn_mfma_f32_16x16x32_bf16(af[m],  bfr[n], accS[m][n], 0, 0, 0);
                accQ[m][n] = __builtin_amdgcn_mfma_f32_16x16x32_bf16(a2f[m], b2f[n], accQ[m][n], 0, 0, 0);
            }
    }
#pragma unroll
    for (int m = 0; m < 4; ++m) {
        const int grow0 = mbase + wr * 64 + m * 16 + lk * 4;
#pragma unroll
        for (int n = 0; n < 4; ++n) {
            const int gcol = nbase + wc * 64 + n * 16 + lr;
            if (gcol < NM) {
                f32x4 s = accS[m][n]; f32x4 q = accQ[m][n];
#pragma unroll
                for (int r = 0; r < 4; ++r) {
                    const int grow = grow0 + r;
                    if (grow < NU)
                        out[(size_t)grow * NM + gcol] = 0.5f * (s[r]*s[r] - q[r]);
                }
            }
        }
    }
}

extern "C" void kernel_launch(void* const* d_in, const int* in_sizes, int n_in,
                              void* d_out, int out_size, void* d_ws, size_t ws_size,
                              hipStream_t stream) {
    const float* U = (const float*)d_in[0];
    const float* M = (const float*)d_in[1];
    float* out = (float*)d_out;
    const int NU = in_sizes[0] / DK;   // 1024
    const int NM = in_sizes[1] / DK;   // 50000
    const int NUP = ((NU + 63) / 64) * 64;
    const int NMP = ((NM + 127) / 128) * 128;
    const size_t need = (size_t)(NUP + NMP) * DK * 2 * sizeof(short);

    if ((NU % 64 == 0) && ws_size >= need) {
        short* ws = (short*)d_ws;
        const int tasks = (NUP + NMP) * 8;
        fm_convert<<<(tasks + 255) / 256, 256, 0, stream>>>(U, M, ws, NU, NM, NUP, NMP);
        dim3 grid(NU / BM, NMP / BN);
        fm_gemm<<<grid, dim3(256), 0, stream>>>(ws, out, NM, NMP, NUP);
    } else {
        dim3 grid((NU + 127) / 128, (NM + 127) / 128);
        fm_fallback<<<grid, dim3(256), 0, stream>>>(U, M, out, NU, NM);
    }
}